// Round 1
// baseline (242.811 us; speedup 1.0000x reference)
//
#include <hip/hip_runtime.h>

#define HWD 884736   // 96*96*96
#define KCLS 5
#define CCH 64
#define NC 4
#define PADC 72      // class stride in LDS: classes land 8 banks apart

constexpr int TPB = 256;
constexpr int VPT = 4;                     // voxels per thread
constexpr int CHUNK = TPB * VPT;           // 1024 voxels per block-iteration
constexpr int NCHUNKS = 2 * HWD / CHUNK;   // 1728 (exact, no straddle of b)
constexpr int NPART = 8;
constexpr int PARTSZ = 272;                // 256 sums + 4 cnt + 4 sumsq + pad
constexpr int GRID1 = 864;                 // 2 chunks per block

__global__ __launch_bounds__(TPB) void pm_pass1(
    const float* __restrict__ feat, const float* __restrict__ pred,
    const int* __restrict__ label, const unsigned char* __restrict__ is_lab,
    float* __restrict__ part)
{
    __shared__ float lsum[NC * PADC];
    __shared__ float lcnt[NC];
    __shared__ float lsq[NC];
    const int t = threadIdx.x;
    for (int i = t; i < NC * PADC; i += TPB) lsum[i] = 0.f;
    if (t < NC) { lcnt[t] = 0.f; lsq[t] = 0.f; }
    __syncthreads();

    for (int chunk = blockIdx.x; chunk < NCHUNKS; chunk += gridDim.x) {
        const int gvox = chunk * CHUNK + t * VPT;
        const int b = gvox / HWD;
        const int s = gvox - b * HWD;

        const float4* pb = (const float4*)(pred + (size_t)b * KCLS * HWD + s);
        float4 pk[KCLS];
        #pragma unroll
        for (int k = 0; k < KCLS; ++k) pk[k] = pb[(size_t)k * (HWD / 4)];
        const int4 lb = *(const int4*)(label + (size_t)b * HWD + s);
        const bool lab = is_lab[b] != 0;

        int q[VPT]; bool m[VPT];
        #pragma unroll
        for (int j = 0; j < VPT; ++j) {
            float best = -1.f; int bi = 0;
            #pragma unroll
            for (int k = 0; k < KCLS; ++k) {
                float v = ((const float*)&pk[k])[j];
                if (v > best) { best = v; bi = k; }   // first-max, matches argmax
            }
            const int lj = ((const int*)&lb)[j];
            m[j] = (best > 0.8f) & (bi > 0) & ((bi == lj) | (!lab));
            q[j] = bi - 1;
        }

        if (m[0] | m[1] | m[2] | m[3]) {
            const float4* fb = (const float4*)(feat + (size_t)b * CCH * HWD + s);
            float sq[VPT] = {0.f, 0.f, 0.f, 0.f};
            #pragma unroll 8
            for (int c = 0; c < CCH; ++c) {
                float4 f = fb[(size_t)c * (HWD / 4)];
                #pragma unroll
                for (int j = 0; j < VPT; ++j) {
                    float v = ((const float*)&f)[j];
                    if (m[j]) { atomicAdd(&lsum[q[j] * PADC + c], v); sq[j] += v * v; }
                }
            }
            #pragma unroll
            for (int j = 0; j < VPT; ++j) if (m[j]) {
                atomicAdd(&lcnt[q[j]], 1.0f);
                atomicAdd(&lsq[q[j]], sq[j]);
            }
        }
    }
    __syncthreads();

    // flush block partials to one of NPART global accumulators
    float* dst = part + (size_t)(blockIdx.x & (NPART - 1)) * PARTSZ;
    const int q = t >> 6, c = t & 63;
    const float v = lsum[q * PADC + c];
    if (v != 0.f) atomicAdd(&dst[t], v);
    if (t < NC) { float w = lcnt[t]; if (w != 0.f) atomicAdd(&dst[256 + t], w); }
    if (t >= NC && t < 2 * NC) { float w = lsq[t - NC]; if (w != 0.f) atomicAdd(&dst[256 + t], w); }
}

__global__ __launch_bounds__(256) void pm_pass2(
    const float* __restrict__ part, const float* __restrict__ proto,
    float* __restrict__ out)
{
    __shared__ float scnt[NC], ssq[NC], smu[NC * CCH], sred[4];
    __shared__ float s_intra;
    const int t = threadIdx.x;
    const int q = t >> 6;

    float s = 0.f;
    #pragma unroll
    for (int p = 0; p < NPART; ++p) s += part[p * PARTSZ + t];
    if (t < 2 * NC) {
        float a = 0.f;
        #pragma unroll
        for (int p = 0; p < NPART; ++p) a += part[p * PARTSZ + 256 + t];
        if (t < NC) scnt[t] = a; else ssq[t - NC] = a;
    }
    __syncthreads();

    const float cq = scnt[q];
    const float mean = s / fmaxf(cq, 1.f);
    const float pold = proto[t];                       // (4,64) row-major == t
    const float mu = (cq > 0.f) ? 0.9f * pold + 0.1f * mean : pold;
    out[3 + t] = mu;
    smu[t] = mu;

    // loss_intra numerator partial: -2*sums*mu + cnt*mu^2  (sumsq added later)
    float pi = -2.f * s * mu + cq * mu * mu;
    #pragma unroll
    for (int o = 1; o < 64; o <<= 1) pi += __shfl_xor(pi, o);
    if ((t & 63) == 0) sred[t >> 6] = pi;
    __syncthreads();

    if (t == 0) {
        float num = sred[0] + sred[1] + sred[2] + sred[3]
                  + ssq[0] + ssq[1] + ssq[2] + ssq[3];
        float nv = scnt[0] + scnt[1] + scnt[2] + scnt[3];
        s_intra = num / fmaxf(nv, 1.f);
    }
    __syncthreads();

    if (t < 64) {
        const int pi_[6] = {0, 0, 0, 1, 1, 2};
        const int pj_[6] = {1, 2, 3, 2, 3, 3};
        float acc = 0.f;
        #pragma unroll
        for (int e = 0; e < 6; ++e) {
            float d = smu[pi_[e] * 64 + t] - smu[pj_[e] * 64 + t];
            float d2 = d * d;
            #pragma unroll
            for (int o = 1; o < 64; o <<= 1) d2 += __shfl_xor(d2, o);
            float dist = sqrtf(d2 + 1e-12f);
            float vv = fmaxf(1.f - dist, 0.f);
            acc += vv * vv;
        }
        if (t == 0) {
            float li = acc / 6.f;                      // n_pairs = 6
            out[0] = s_intra + 0.1f * li;              // lambda_intra=1, lambda_inter=0.1
            out[1] = s_intra;
            out[2] = li;
        }
    }
}

extern "C" void kernel_launch(void* const* d_in, const int* in_sizes, int n_in,
                              void* d_out, int out_size, void* d_ws, size_t ws_size,
                              hipStream_t stream) {
    const float* feat         = (const float*)d_in[0];
    const float* pred         = (const float*)d_in[1];
    const int* label          = (const int*)d_in[2];
    const unsigned char* ilab = (const unsigned char*)d_in[3];   // jnp bool = 1 byte
    const float* proto        = (const float*)d_in[4];
    float* out                = (float*)d_out;
    float* part               = (float*)d_ws;

    hipMemsetAsync(d_ws, 0, NPART * PARTSZ * sizeof(float), stream);
    hipLaunchKernelGGL(pm_pass1, dim3(GRID1), dim3(TPB), 0, stream,
                       feat, pred, label, ilab, part);
    hipLaunchKernelGGL(pm_pass2, dim3(1), dim3(256), 0, stream, part, proto, out);
}

// Round 2
// 233.870 us; speedup vs baseline: 1.0382x; 1.0382x over previous
//
#include <hip/hip_runtime.h>

#define HWD 884736   // 96*96*96
#define KCLS 5
#define CCH 64
#define NC 4
#define PADC 72      // class stride in LDS: classes land 8 banks apart

constexpr int TPB = 256;
constexpr int VPT = 4;                     // voxels per thread
constexpr int CHUNK = TPB * VPT;           // 1024 voxels per block
constexpr int NCHUNKS = 2 * HWD / CHUNK;   // 1728 (exact, no straddle of b)
constexpr int NPART = 16;
constexpr int PARTSZ = 272;                // 256 sums + 4 cnt + 4 sumsq + pad

__global__ __launch_bounds__(256) void pm_zero(float* __restrict__ part) {
    const int n = NPART * PARTSZ;
    for (int i = threadIdx.x; i < n; i += 256) part[i] = 0.f;
}

__global__ __launch_bounds__(TPB) void pm_pass1(
    const float* __restrict__ feat, const float* __restrict__ pred,
    const int* __restrict__ label, const unsigned char* __restrict__ is_lab,
    float* __restrict__ part)
{
    __shared__ float lsum[NC * PADC];
    __shared__ float lcnt[NC];
    __shared__ float lsq[NC];
    const int t = threadIdx.x;
    for (int i = t; i < NC * PADC; i += TPB) lsum[i] = 0.f;
    if (t < NC) { lcnt[t] = 0.f; lsq[t] = 0.f; }
    __syncthreads();

    const int chunk = blockIdx.x;            // grid == NCHUNKS
    const int gvox = chunk * CHUNK + t * VPT;
    const int b = gvox / HWD;
    const int s = gvox - b * HWD;

    const float4* pb = (const float4*)(pred + (size_t)b * KCLS * HWD + s);
    float4 pk[KCLS];
    #pragma unroll
    for (int k = 0; k < KCLS; ++k) pk[k] = pb[(size_t)k * (HWD / 4)];
    const int4 lb = *(const int4*)(label + (size_t)b * HWD + s);
    const bool lab = is_lab[b] != 0;

    int q[VPT]; bool m[VPT];
    #pragma unroll
    for (int j = 0; j < VPT; ++j) {
        float best = -1.f; int bi = 0;
        #pragma unroll
        for (int k = 0; k < KCLS; ++k) {
            float v = ((const float*)&pk[k])[j];
            if (v > best) { best = v; bi = k; }   // first-max, matches argmax
        }
        const int lj = ((const int*)&lb)[j];
        m[j] = (((const float*)&pk[0])[j] < best) &   // == (bi > 0) via first-max
               (best > 0.8f) & ((bi == lj) | (!lab));
        m[j] = (best > 0.8f) & (bi > 0) & ((bi == lj) | (!lab));
        q[j] = bi - 1;
    }

    if (m[0] | m[1] | m[2] | m[3]) {
        const float4* fb = (const float4*)(feat + (size_t)b * CCH * HWD + s);
        float sq[VPT] = {0.f, 0.f, 0.f, 0.f};
        #pragma unroll
        for (int cg = 0; cg < CCH / 8; ++cg) {
            float4 f[8];
            #pragma unroll
            for (int u = 0; u < 8; ++u)
                f[u] = fb[(size_t)(cg * 8 + u) * (HWD / 4)];
            #pragma unroll
            for (int u = 0; u < 8; ++u) {
                const int c = cg * 8 + u;
                #pragma unroll
                for (int j = 0; j < VPT; ++j) {
                    float v = ((const float*)&f[u])[j];
                    if (m[j]) { atomicAdd(&lsum[q[j] * PADC + c], v); sq[j] += v * v; }
                }
            }
        }
        #pragma unroll
        for (int j = 0; j < VPT; ++j) if (m[j]) {
            atomicAdd(&lcnt[q[j]], 1.0f);
            atomicAdd(&lsq[q[j]], sq[j]);
        }
    }
    __syncthreads();

    // flush block partials into one of NPART global accumulators
    float* dst = part + (size_t)(blockIdx.x & (NPART - 1)) * PARTSZ;
    const float v = lsum[(t >> 6) * PADC + (t & 63)];
    if (v != 0.f) atomicAdd(&dst[t], v);
    if (t < NC) { float w = lcnt[t]; if (w != 0.f) atomicAdd(&dst[256 + t], w); }
    if (t >= NC && t < 2 * NC) { float w = lsq[t - NC]; if (w != 0.f) atomicAdd(&dst[256 + t], w); }
}

__global__ __launch_bounds__(256) void pm_pass2(
    const float* __restrict__ part, const float* __restrict__ proto,
    float* __restrict__ out)
{
    __shared__ float scnt[NC], ssq[NC], smu[NC * CCH], sred[4];
    __shared__ float s_intra;
    const int t = threadIdx.x;
    const int q = t >> 6;

    float s = 0.f;
    #pragma unroll
    for (int p = 0; p < NPART; ++p) s += part[p * PARTSZ + t];
    if (t < 2 * NC) {
        float a = 0.f;
        #pragma unroll
        for (int p = 0; p < NPART; ++p) a += part[p * PARTSZ + 256 + t];
        if (t < NC) scnt[t] = a; else ssq[t - NC] = a;
    }
    __syncthreads();

    const float cq = scnt[q];
    const float mean = s / fmaxf(cq, 1.f);
    const float pold = proto[t];                       // (4,64) row-major == t
    const float mu = (cq > 0.f) ? 0.9f * pold + 0.1f * mean : pold;
    out[3 + t] = mu;
    smu[t] = mu;

    // loss_intra numerator partial: -2*sums*mu + cnt*mu^2  (sumsq added at the end)
    float pi = -2.f * s * mu + cq * mu * mu;
    #pragma unroll
    for (int o = 1; o < 64; o <<= 1) pi += __shfl_xor(pi, o);
    if ((t & 63) == 0) sred[t >> 6] = pi;
    __syncthreads();

    if (t == 0) {
        float num = sred[0] + sred[1] + sred[2] + sred[3]
                  + ssq[0] + ssq[1] + ssq[2] + ssq[3];
        float nv = scnt[0] + scnt[1] + scnt[2] + scnt[3];
        s_intra = num / fmaxf(nv, 1.f);
    }
    __syncthreads();

    if (t < 64) {
        const int pi_[6] = {0, 0, 0, 1, 1, 2};
        const int pj_[6] = {1, 2, 3, 2, 3, 3};
        float acc = 0.f;
        #pragma unroll
        for (int e = 0; e < 6; ++e) {
            float d = smu[pi_[e] * 64 + t] - smu[pj_[e] * 64 + t];
            float d2 = d * d;
            #pragma unroll
            for (int o = 1; o < 64; o <<= 1) d2 += __shfl_xor(d2, o);
            float dist = sqrtf(d2 + 1e-12f);
            float vv = fmaxf(1.f - dist, 0.f);
            acc += vv * vv;
        }
        if (t == 0) {
            float li = acc / 6.f;                      // n_pairs = 6
            out[0] = s_intra + 0.1f * li;              // lambda_intra=1, lambda_inter=0.1
            out[1] = s_intra;
            out[2] = li;
        }
    }
}

extern "C" void kernel_launch(void* const* d_in, const int* in_sizes, int n_in,
                              void* d_out, int out_size, void* d_ws, size_t ws_size,
                              hipStream_t stream) {
    const float* feat         = (const float*)d_in[0];
    const float* pred         = (const float*)d_in[1];
    const int* label          = (const int*)d_in[2];
    const unsigned char* ilab = (const unsigned char*)d_in[3];   // jnp bool = 1 byte
    const float* proto        = (const float*)d_in[4];
    float* out                = (float*)d_out;
    float* part               = (float*)d_ws;

    hipLaunchKernelGGL(pm_zero, dim3(1), dim3(256), 0, stream, part);
    hipLaunchKernelGGL(pm_pass1, dim3(NCHUNKS), dim3(TPB), 0, stream,
                       feat, pred, label, ilab, part);
    hipLaunchKernelGGL(pm_pass2, dim3(1), dim3(256), 0, stream, part, proto, out);
}

// Round 4
// 136.570 us; speedup vs baseline: 1.7779x; 1.7125x over previous
//
#include <hip/hip_runtime.h>

#define HWD 884736   // 96*96*96
#define KCLS 5
#define CCH 64
#define NC 4

constexpr int TPB = 256;
constexpr int VPT = 4;                     // voxels per thread-group entry
constexpr int CHUNK = TPB * VPT;           // 1024 voxels per block
constexpr int NCHUNKS = 2 * HWD / CHUNK;   // 1728 (b never straddles a block)
constexpr int NPART = 16;
constexpr int PARTSZ = 272;                // 256 sums + 4 cnt @256 + 4 sq @260

__global__ __launch_bounds__(256) void pm_zero(float* __restrict__ part) {
    const int n = NPART * PARTSZ;
    for (int i = threadIdx.x; i < n; i += 256) part[i] = 0.f;
}

__global__ __launch_bounds__(TPB) void pm_pass1(
    const float* __restrict__ feat, const float* __restrict__ pred,
    const int* __restrict__ label, const unsigned char* __restrict__ is_lab,
    float* __restrict__ part)
{
    __shared__ int   wl[TPB];          // packed worklist: srct<<12 | 3b*4 (valid|class)
    __shared__ int   nwl;
    __shared__ float lcnt[NC];
    __shared__ float lacc [4][NC][CCH];  // [wave][class][chan] sums
    __shared__ float lacc2[4][NC][CCH];  // [wave][class][chan] sumsq

    const int t = threadIdx.x;
    const int w = t >> 6, lane = t & 63;
    if (t == 0) nwl = 0;
    if (t < NC) lcnt[t] = 0.f;
    __syncthreads();

    const int chunk = blockIdx.x;
    const int b = (chunk >= NCHUNKS / 2) ? 1 : 0;     // HWD % CHUNK == 0
    const int s = chunk * CHUNK - b * HWD + t * VPT;  // spatial offset of this group

    // ---- phase 1: mask from pred/label (coalesced), build worklist ----
    {
        const float4* pb = (const float4*)(pred + (size_t)b * KCLS * HWD + s);
        float4 pk[KCLS];
        #pragma unroll
        for (int k = 0; k < KCLS; ++k) pk[k] = pb[(size_t)k * (HWD / 4)];
        const int4 lb = *(const int4*)(label + (size_t)b * HWD + s);
        const bool lab = is_lab[b] != 0;

        int pack = 0;
        #pragma unroll
        for (int j = 0; j < VPT; ++j) {
            float best = -1.f; int bi = 0;
            #pragma unroll
            for (int k = 0; k < KCLS; ++k) {
                float v = ((const float*)&pk[k])[j];
                if (v > best) { best = v; bi = k; }   // first-max == jnp.argmax
            }
            const int lj = ((const int*)&lb)[j];
            const bool m = (best > 0.8f) & (bi > 0) & ((bi == lj) | (!lab));
            if (m) {
                pack |= (4 | (bi - 1)) << (3 * j);
                atomicAdd(&lcnt[bi - 1], 1.0f);
            }
        }
        if (pack) wl[atomicAdd(&nwl, 1)] = pack | (t << 12);
    }
    __syncthreads();

    // ---- phase 2: cooperative feat reads; lane c owns channel c ----
    float accs[NC] = {0.f, 0.f, 0.f, 0.f};
    float accq[NC] = {0.f, 0.f, 0.f, 0.f};
    {
        const int n = nwl;
        const float4* fb = (const float4*)(feat + (size_t)b * CCH * HWD);
        const size_t laneoff = (size_t)lane * (HWD / 4) + (size_t)chunk * (CHUNK / 4)
                             - (size_t)b * (HWD / 4);
        for (int i0 = w; i0 < n; i0 += 16) {           // 4 entries per wave per batch
            int e[4];
            #pragma unroll
            for (int u = 0; u < 4; ++u) {
                const int i = i0 + 4 * u;
                e[u] = (i < n) ? wl[i] : 0;            // wave-uniform predicate
            }
            float4 f[4];
            #pragma unroll
            for (int u = 0; u < 4; ++u)
                if (e[u]) f[u] = fb[laneoff + (e[u] >> 12)];   // 4 loads in flight
            #pragma unroll
            for (int u = 0; u < 4; ++u) {
                if (!e[u]) continue;
                #pragma unroll
                for (int j = 0; j < VPT; ++j) {
                    const int bits = (e[u] >> (3 * j)) & 7;
                    if (bits & 4) {
                        const int q = bits & 3;
                        const float v = ((const float*)&f[u])[j];
                        const float v2 = v * v;
                        #pragma unroll
                        for (int k = 0; k < NC; ++k)
                            if (q == k) { accs[k] += v; accq[k] += v2; }
                    }
                }
            }
        }
    }
    #pragma unroll
    for (int k = 0; k < NC; ++k) { lacc[w][k][lane] = accs[k]; lacc2[w][k][lane] = accq[k]; }
    __syncthreads();

    // ---- phase 3: cross-wave reduce, flush to one of NPART buckets ----
    float* dst = part + (size_t)(blockIdx.x & (NPART - 1)) * PARTSZ;
    const int q = t >> 6, c = t & 63;
    float vs = lacc [0][q][c] + lacc [1][q][c] + lacc [2][q][c] + lacc [3][q][c];
    float vq = lacc2[0][q][c] + lacc2[1][q][c] + lacc2[2][q][c] + lacc2[3][q][c];
    if (vs != 0.f) atomicAdd(&dst[t], vs);
    #pragma unroll
    for (int o = 1; o < 64; o <<= 1) vq += __shfl_xor(vq, o);
    if (c == 0 && vq != 0.f) atomicAdd(&dst[260 + q], vq);
    if (t < NC) { float cv = lcnt[t]; if (cv != 0.f) atomicAdd(&dst[256 + t], cv); }
}

__global__ __launch_bounds__(256) void pm_pass2(
    const float* __restrict__ part, const float* __restrict__ proto,
    float* __restrict__ out)
{
    __shared__ float scnt[NC], ssq[NC], smu[NC * CCH], sred[4];
    __shared__ float s_intra;
    const int t = threadIdx.x;
    const int q = t >> 6;

    float s = 0.f;
    #pragma unroll
    for (int p = 0; p < NPART; ++p) s += part[p * PARTSZ + t];
    if (t < 2 * NC) {
        float a = 0.f;
        #pragma unroll
        for (int p = 0; p < NPART; ++p) a += part[p * PARTSZ + 256 + t];
        if (t < NC) scnt[t] = a; else ssq[t - NC] = a;
    }
    __syncthreads();

    const float cq = scnt[q];
    const float mean = s / fmaxf(cq, 1.f);
    const float pold = proto[t];                       // (4,64) row-major == t
    const float mu = (cq > 0.f) ? 0.9f * pold + 0.1f * mean : pold;
    out[3 + t] = mu;
    smu[t] = mu;

    // loss_intra numerator partial: -2*sums*mu + cnt*mu^2  (sumsq added at the end)
    float pi = -2.f * s * mu + cq * mu * mu;
    #pragma unroll
    for (int o = 1; o < 64; o <<= 1) pi += __shfl_xor(pi, o);
    if ((t & 63) == 0) sred[t >> 6] = pi;
    __syncthreads();

    if (t == 0) {
        float num = sred[0] + sred[1] + sred[2] + sred[3]
                  + ssq[0] + ssq[1] + ssq[2] + ssq[3];
        float nv = scnt[0] + scnt[1] + scnt[2] + scnt[3];
        s_intra = num / fmaxf(nv, 1.f);
    }
    __syncthreads();

    if (t < 64) {
        const int pi_[6] = {0, 0, 0, 1, 1, 2};
        const int pj_[6] = {1, 2, 3, 2, 3, 3};
        float acc = 0.f;
        #pragma unroll
        for (int e = 0; e < 6; ++e) {
            float d = smu[pi_[e] * 64 + t] - smu[pj_[e] * 64 + t];
            float d2 = d * d;
            #pragma unroll
            for (int o = 1; o < 64; o <<= 1) d2 += __shfl_xor(d2, o);
            float dist = sqrtf(d2 + 1e-12f);
            float vv = fmaxf(1.f - dist, 0.f);
            acc += vv * vv;
        }
        if (t == 0) {
            float li = acc / 6.f;                      // n_pairs = 6
            out[0] = s_intra + 0.1f * li;              // lambda_intra=1, lambda_inter=0.1
            out[1] = s_intra;
            out[2] = li;
        }
    }
}

extern "C" void kernel_launch(void* const* d_in, const int* in_sizes, int n_in,
                              void* d_out, int out_size, void* d_ws, size_t ws_size,
                              hipStream_t stream) {
    const float* feat         = (const float*)d_in[0];
    const float* pred         = (const float*)d_in[1];
    const int* label          = (const int*)d_in[2];
    const unsigned char* ilab = (const unsigned char*)d_in[3];   // jnp bool = 1 byte
    const float* proto        = (const float*)d_in[4];
    float* out                = (float*)d_out;
    float* part               = (float*)d_ws;

    hipLaunchKernelGGL(pm_zero, dim3(1), dim3(256), 0, stream, part);
    hipLaunchKernelGGL(pm_pass1, dim3(NCHUNKS), dim3(TPB), 0, stream,
                       feat, pred, label, ilab, part);
    hipLaunchKernelGGL(pm_pass2, dim3(1), dim3(256), 0, stream, part, proto, out);
}